// Round 2
// baseline (1344.749 us; speedup 1.0000x reference)
//
#include <hip/hip_runtime.h>

#define N_NODES 50000
#define N_EDGES 1600000
#define HEADS 8
#define HIDDEN 64
#define FAN_IN (2*HIDDEN + 1)
#define EPSF 1e-16f

// Edge pass: per-block precompute per-head affine constants in LDS, then
// one thread per edge computes 8 head scores and atomically accumulates
// S[n,k] = sum exp(raw), T[n,k] = sum f_src*exp(raw) over incoming edges.
__global__ __launch_bounds__(256) void cagat_edge_kernel(
    const float* __restrict__ nf,     // node_features [N]
    const float* __restrict__ cmask,  // cycle_mask [E]
    const float* __restrict__ Wp,     // W_proj [64,1]
    const float* __restrict__ bp,     // b_proj [64]
    const float* __restrict__ Wa,     // W_att [8,129]
    const float* __restrict__ ba,     // b_att [8]
    const float* __restrict__ cp,     // cycle_penalty [8]
    const int*   __restrict__ ei,     // edge_index [2,E] (int32)
    float* __restrict__ S,            // [N*8]
    float* __restrict__ T)            // [N*8]
{
    __shared__ float A1[HEADS], A2[HEADS], CC[HEADS], DD[HEADS], PP[HEADS];
    const int t = threadIdx.x;
    if (t < HEADS) {
        const float* row = Wa + t * FAN_IN;
        float a1 = 0.f, a2 = 0.f, b1 = 0.f, b2 = 0.f;
        for (int h = 0; h < HIDDEN; ++h) {
            float w = Wp[h];
            float b = bp[h];
            a1 += w * row[h];
            a2 += w * row[HIDDEN + h];
            b1 += b * row[h];
            b2 += b * row[HIDDEN + h];
        }
        A1[t] = a1;
        A2[t] = a2;
        CC[t] = row[2*HIDDEN];
        DD[t] = b1 + b2 + ba[t];
        PP[t] = cp[t];
    }
    __syncthreads();

    const int e = blockIdx.x * 256 + t;
    if (e >= N_EDGES) return;

    const int src = ei[e];
    const int dst = ei[N_EDGES + e];
    const float fs = nf[src];
    const float fd = nf[dst];
    const float c  = cmask[e];

    float* Sd = S + dst * HEADS;
    float* Td = T + dst * HEADS;
    #pragma unroll
    for (int k = 0; k < HEADS; ++k) {
        float r = fs * A1[k] + fd * A2[k] + c * CC[k] + DD[k];
        r = (r >= 0.f) ? r : 0.2f * r;       // LeakyReLU(0.2)
        r += c * PP[k];                      // cycle penalty
        float ev = __expf(r);
        atomicAdd(Sd + k, ev);
        atomicAdd(Td + k, fs * ev);
    }
}

// Node pass: out[n] = scaler/8 * sum_k T[n,k] / (S[n,k] + eps)
__global__ __launch_bounds__(256) void cagat_node_kernel(
    const float* __restrict__ S,
    const float* __restrict__ T,
    const float* __restrict__ scaler,
    float* __restrict__ out)
{
    const int n = blockIdx.x * 256 + threadIdx.x;
    if (n >= N_NODES) return;
    const float4* S4 = (const float4*)(S + n * HEADS);
    const float4* T4 = (const float4*)(T + n * HEADS);
    float4 s0 = S4[0], s1 = S4[1];
    float4 t0 = T4[0], t1 = T4[1];
    float acc = t0.x / (s0.x + EPSF) + t0.y / (s0.y + EPSF)
              + t0.z / (s0.z + EPSF) + t0.w / (s0.w + EPSF)
              + t1.x / (s1.x + EPSF) + t1.y / (s1.y + EPSF)
              + t1.z / (s1.z + EPSF) + t1.w / (s1.w + EPSF);
    out[n] = acc * 0.125f * scaler[0];
}

extern "C" void kernel_launch(void* const* d_in, const int* in_sizes, int n_in,
                              void* d_out, int out_size, void* d_ws, size_t ws_size,
                              hipStream_t stream) {
    const float* nf    = (const float*)d_in[0];
    const float* cmask = (const float*)d_in[1];
    const float* Wp    = (const float*)d_in[2];
    const float* bp    = (const float*)d_in[3];
    const float* Wa    = (const float*)d_in[4];
    const float* ba    = (const float*)d_in[5];
    const float* cp    = (const float*)d_in[6];
    const float* sc    = (const float*)d_in[7];
    const int*   ei    = (const int*)d_in[8];

    float* S = (float*)d_ws;
    float* T = S + (size_t)N_NODES * HEADS;

    // Zero the S/T accumulators (ws is poisoned 0xAA before every launch).
    hipMemsetAsync(d_ws, 0, (size_t)N_NODES * HEADS * 2 * sizeof(float), stream);

    cagat_edge_kernel<<<(N_EDGES + 255) / 256, 256, 0, stream>>>(
        nf, cmask, Wp, bp, Wa, ba, cp, ei, S, T);

    cagat_node_kernel<<<(N_NODES + 255) / 256, 256, 0, stream>>>(
        S, T, sc, (float*)d_out);
}

// Round 3
// 212.682 us; speedup vs baseline: 6.3228x; 6.3228x over previous
//
#include <hip/hip_runtime.h>

#define N_NODES 50000
#define N_EDGES 1600000
#define HEADS 8
#define HIDDEN 64
#define FAN_IN (2*HIDDEN + 1)
#define EPSF 1e-16f

// ---------------- workspace layout (bytes) ----------------
#define CNT_OFF      0          // 50176 ints (padded, zeroed each launch)
#define START_OFF    262144     // 50001 ints (exclusive prefix; start[N]=E)
#define BSUM_OFF     524288     // 196 ints
#define BPRE_OFF     528384     // 256 ints
#define CONST_OFF    532480     // 40 floats: A1[8]|A2[8]|CC[8]|DD[8]|PP[8]
#define RANK_OFF     1048576    // 1.6M ints (rank of edge within its dst)
#define PAYLOAD_OFF  8388608    // 1.6M float2 (f_src, cmask) sorted by dst
#define WS_NEEDED    (PAYLOAD_OFF + (size_t)N_EDGES * 8)

#define NB_SCAN 196             // 196*256 = 50176 >= 50000

// Precompute per-head affine constants:
// raw[e,k] = fs*A1[k] + fd*A2[k] + c*(CC[k]) + DD[k]  (then leaky-relu, then +c*PP[k])
__global__ void k_prep(const float* __restrict__ Wp, const float* __restrict__ bp,
                       const float* __restrict__ Wa, const float* __restrict__ ba,
                       const float* __restrict__ cp, float* __restrict__ cst) {
    const int k = threadIdx.x;
    if (k >= HEADS) return;
    const float* row = Wa + k * FAN_IN;
    float a1 = 0.f, a2 = 0.f, d = 0.f;
    for (int h = 0; h < HIDDEN; ++h) {
        float w = Wp[h], b = bp[h];
        a1 += w * row[h];
        a2 += w * row[HIDDEN + h];
        d  += b * (row[h] + row[HIDDEN + h]);
    }
    cst[k]      = a1;
    cst[8 + k]  = a2;
    cst[16 + k] = row[2 * HIDDEN];
    cst[24 + k] = d + ba[k];
    cst[32 + k] = cp[k];
}

// Histogram of dst + per-edge rank (returned old count).
__global__ __launch_bounds__(256) void k_hist(const int* __restrict__ ei,
                                              int* __restrict__ cnt,
                                              int* __restrict__ rank) {
    const int e = blockIdx.x * 256 + threadIdx.x;
    if (e >= N_EDGES) return;
    const int dst = ei[N_EDGES + e];
    rank[e] = atomicAdd(&cnt[dst], 1);
}

// Per-block reduction of counts -> bsum[196]
__global__ __launch_bounds__(256) void k_scan_reduce(const int* __restrict__ cnt,
                                                     int* __restrict__ bsum) {
    __shared__ int lds[256];
    const int t = threadIdx.x;
    lds[t] = cnt[blockIdx.x * 256 + t];
    __syncthreads();
    for (int s = 128; s > 0; s >>= 1) {
        if (t < s) lds[t] += lds[t + s];
        __syncthreads();
    }
    if (t == 0) bsum[blockIdx.x] = lds[0];
}

// Single-block exclusive scan of bsum -> bpre
__global__ __launch_bounds__(256) void k_scan_top(const int* __restrict__ bsum,
                                                  int* __restrict__ bpre) {
    __shared__ int lds[256];
    const int t = threadIdx.x;
    lds[t] = (t < NB_SCAN) ? bsum[t] : 0;
    __syncthreads();
    for (int d = 1; d < 256; d <<= 1) {
        int v = (t >= d) ? lds[t - d] : 0;
        __syncthreads();
        lds[t] += v;
        __syncthreads();
    }
    bpre[t] = (t == 0) ? 0 : lds[t - 1];
}

// Per-block local scan + block prefix -> start[] (exclusive; start[N_NODES]=E)
__global__ __launch_bounds__(256) void k_scan_local(const int* __restrict__ cnt,
                                                    const int* __restrict__ bpre,
                                                    int* __restrict__ start) {
    __shared__ int lds[256];
    const int t = threadIdx.x;
    const int i = blockIdx.x * 256 + t;
    const int v = cnt[i];
    lds[t] = v;
    __syncthreads();
    for (int d = 1; d < 256; d <<= 1) {
        int x = (t >= d) ? lds[t - d] : 0;
        __syncthreads();
        lds[t] += x;
        __syncthreads();
    }
    const int excl = lds[t] - v + bpre[blockIdx.x];
    if (i <= N_NODES) start[i] = excl;
}

// Scatter edges into dst-sorted order. No atomics.
__global__ __launch_bounds__(256) void k_scatter(const int* __restrict__ ei,
                                                 const float* __restrict__ cmask,
                                                 const float* __restrict__ nf,
                                                 const int* __restrict__ start,
                                                 const int* __restrict__ rank,
                                                 float2* __restrict__ payload) {
    const int e = blockIdx.x * 256 + threadIdx.x;
    if (e >= N_EDGES) return;
    const int src = ei[e];
    const int dst = ei[N_EDGES + e];
    const int pos = start[dst] + rank[e];
    payload[pos] = make_float2(nf[src], cmask[e]);
}

// Gather-reduce: 16 lanes per node, edges contiguous, no atomics.
__global__ __launch_bounds__(256) void k_reduce(const float* __restrict__ nf,
                                                const float* __restrict__ cst_g,
                                                const int* __restrict__ start,
                                                const float2* __restrict__ payload,
                                                const float* __restrict__ scaler,
                                                float* __restrict__ out) {
    __shared__ float cst[40];
    __shared__ float ssc;
    const int t = threadIdx.x;
    if (t < 40) cst[t] = cst_g[t];
    if (t == 40) ssc = scaler[0] * 0.125f;
    __syncthreads();

    const int grp  = t >> 4;           // 16 groups of 16 lanes
    const int lane = t & 15;
    const int n = blockIdx.x * 16 + grp;
    if (n >= N_NODES) return;

    const int s0 = start[n], s1 = start[n + 1];
    const float fd = nf[n];

    float as[HEADS], at[HEADS];
    #pragma unroll
    for (int k = 0; k < HEADS; ++k) { as[k] = 0.f; at[k] = 0.f; }

    for (int i = s0 + lane; i < s1; i += 16) {
        const float2 p = payload[i];
        const float fs = p.x, c = p.y;
        #pragma unroll
        for (int k = 0; k < HEADS; ++k) {
            float r = fs * cst[k] + fd * cst[8 + k] + c * cst[16 + k] + cst[24 + k];
            r = (r >= 0.f) ? r : 0.2f * r;
            r += c * cst[32 + k];
            const float ev = __expf(r);
            as[k] += ev;
            at[k] += fs * ev;
        }
    }

    // butterfly reduce within the 16-lane group
    #pragma unroll
    for (int d = 8; d > 0; d >>= 1) {
        #pragma unroll
        for (int k = 0; k < HEADS; ++k) {
            as[k] += __shfl_xor(as[k], d, 16);
            at[k] += __shfl_xor(at[k], d, 16);
        }
    }

    if (lane == 0) {
        float a = 0.f;
        #pragma unroll
        for (int k = 0; k < HEADS; ++k) a += at[k] / (as[k] + EPSF);
        out[n] = a * ssc;
    }
}

// ---------------- fallback (round-2 atomic version) for small ws ----------------
__global__ __launch_bounds__(256) void cagat_edge_atomic(
    const float* __restrict__ nf, const float* __restrict__ cmask,
    const float* __restrict__ Wp, const float* __restrict__ bp,
    const float* __restrict__ Wa, const float* __restrict__ ba,
    const float* __restrict__ cp, const int* __restrict__ ei,
    float* __restrict__ S, float* __restrict__ T) {
    __shared__ float A1[HEADS], A2[HEADS], CC[HEADS], DD[HEADS], PP[HEADS];
    const int t = threadIdx.x;
    if (t < HEADS) {
        const float* row = Wa + t * FAN_IN;
        float a1 = 0.f, a2 = 0.f, d = 0.f;
        for (int h = 0; h < HIDDEN; ++h) {
            float w = Wp[h], b = bp[h];
            a1 += w * row[h]; a2 += w * row[HIDDEN + h];
            d += b * (row[h] + row[HIDDEN + h]);
        }
        A1[t] = a1; A2[t] = a2; CC[t] = row[2*HIDDEN]; DD[t] = d + ba[t]; PP[t] = cp[t];
    }
    __syncthreads();
    const int e = blockIdx.x * 256 + t;
    if (e >= N_EDGES) return;
    const int src = ei[e], dst = ei[N_EDGES + e];
    const float fs = nf[src], fd = nf[dst], c = cmask[e];
    float* Sd = S + dst * HEADS;
    float* Td = T + dst * HEADS;
    #pragma unroll
    for (int k = 0; k < HEADS; ++k) {
        float r = fs * A1[k] + fd * A2[k] + c * CC[k] + DD[k];
        r = (r >= 0.f) ? r : 0.2f * r;
        r += c * PP[k];
        float ev = __expf(r);
        atomicAdd(Sd + k, ev);
        atomicAdd(Td + k, fs * ev);
    }
}

__global__ __launch_bounds__(256) void cagat_node_atomic(
    const float* __restrict__ S, const float* __restrict__ T,
    const float* __restrict__ scaler, float* __restrict__ out) {
    const int n = blockIdx.x * 256 + threadIdx.x;
    if (n >= N_NODES) return;
    float acc = 0.f;
    #pragma unroll
    for (int k = 0; k < HEADS; ++k)
        acc += T[n * HEADS + k] / (S[n * HEADS + k] + EPSF);
    out[n] = acc * 0.125f * scaler[0];
}

extern "C" void kernel_launch(void* const* d_in, const int* in_sizes, int n_in,
                              void* d_out, int out_size, void* d_ws, size_t ws_size,
                              hipStream_t stream) {
    const float* nf    = (const float*)d_in[0];
    const float* cmask = (const float*)d_in[1];
    const float* Wp    = (const float*)d_in[2];
    const float* bp    = (const float*)d_in[3];
    const float* Wa    = (const float*)d_in[4];
    const float* ba    = (const float*)d_in[5];
    const float* cp    = (const float*)d_in[6];
    const float* sc    = (const float*)d_in[7];
    const int*   ei    = (const int*)d_in[8];

    char* ws = (char*)d_ws;

    if (ws_size >= WS_NEEDED) {
        int*    cnt     = (int*)(ws + CNT_OFF);
        int*    start   = (int*)(ws + START_OFF);
        int*    bsum    = (int*)(ws + BSUM_OFF);
        int*    bpre    = (int*)(ws + BPRE_OFF);
        float*  cst     = (float*)(ws + CONST_OFF);
        int*    rank    = (int*)(ws + RANK_OFF);
        float2* payload = (float2*)(ws + PAYLOAD_OFF);

        hipMemsetAsync(cnt, 0, NB_SCAN * 256 * sizeof(int), stream);
        k_prep<<<1, 64, 0, stream>>>(Wp, bp, Wa, ba, cp, cst);
        k_hist<<<(N_EDGES + 255) / 256, 256, 0, stream>>>(ei, cnt, rank);
        k_scan_reduce<<<NB_SCAN, 256, 0, stream>>>(cnt, bsum);
        k_scan_top<<<1, 256, 0, stream>>>(bsum, bpre);
        k_scan_local<<<NB_SCAN, 256, 0, stream>>>(cnt, bpre, start);
        k_scatter<<<(N_EDGES + 255) / 256, 256, 0, stream>>>(ei, cmask, nf, start, rank, payload);
        k_reduce<<<(N_NODES + 15) / 16, 256, 0, stream>>>(nf, cst, start, payload, sc, (float*)d_out);
    } else {
        // fallback: atomic accumulation (needs 3.2 MB)
        float* S = (float*)d_ws;
        float* T = S + (size_t)N_NODES * HEADS;
        hipMemsetAsync(d_ws, 0, (size_t)N_NODES * HEADS * 2 * sizeof(float), stream);
        cagat_edge_atomic<<<(N_EDGES + 255) / 256, 256, 0, stream>>>(
            nf, cmask, Wp, bp, Wa, ba, cp, ei, S, T);
        cagat_node_atomic<<<(N_NODES + 255) / 256, 256, 0, stream>>>(
            S, T, sc, (float*)d_out);
    }
}